// Round 9
// baseline (7396.271 us; speedup 1.0000x reference)
//
#include <hip/hip_runtime.h>
#include <hip/hip_bf16.h>

// LSTM B=32,T=512,D=512,H=1024, persistent kernel.
// R9 = R7 body + 16B sc0|sc1 buffer-loads for h (halves coherence-point op
// count vs 8B atomic loads) + s_sleep(2) poll backoff.
// 16B coherent load via llvm.amdgcn.raw.buffer.load.v4i32 with
// cachepolicy = SC0|SC1 = 17 (bypass L1+L2, serve at coherence point).
// Compiler tracks the dependency and emits its own s_waitcnt (no inline-asm
// register ties, which failed to compile in R8).

#define B_   32
#define T_   512
#define D_   512
#define H_   1024
#define KTOT 1536
#define N4H  4096
#define NBLK 64

typedef __bf16 bf16_t;
typedef __bf16 bf16x8 __attribute__((ext_vector_type(8)));
typedef float f32x4 __attribute__((ext_vector_type(4)));
typedef int   i32x4 __attribute__((ext_vector_type(4)));
typedef unsigned u32x4 __attribute__((ext_vector_type(4)));
typedef unsigned long long ull_t;

// CK-style direct declaration of the raw buffer load intrinsic.
extern "C" __device__ u32x4 llvm_amdgcn_raw_buffer_load_u32x4(
    i32x4 rsrc, int voffset, int soffset, int cachepolicy)
    __asm("llvm.amdgcn.raw.buffer.load.v4i32");

__device__ __forceinline__ i32x4 make_srd(const void* p) {
    union { const void* p; unsigned u[2]; } a;
    a.p = p;
    i32x4 r;
    r.x = (int)a.u[0];
    r.y = (int)(a.u[1] & 0xFFFFu);   // stride = 0
    r.z = -1;                        // num_records = 0xFFFFFFFF (no bounds)
    r.w = 0x00020000;                // raw dword access
    return r;
}

// ---------------------------------------------------------------------------
__global__ void wconv_kernel(const float* __restrict__ Wx,
                             const float* __restrict__ Wh,
                             bf16_t* __restrict__ Wt) {
    __shared__ float tile[32][33];
    int k0 = blockIdx.x * 32;
    int n0 = blockIdx.y * 32;
    int tx = threadIdx.x;
    int ty = threadIdx.y;
    for (int i = ty; i < 32; i += 8) {
        int k = k0 + i;
        float v = (k < H_) ? Wh[(size_t)k * N4H + n0 + tx]
                           : Wx[(size_t)(k - H_) * N4H + n0 + tx];
        tile[i][tx] = v;
    }
    __syncthreads();
    for (int i = ty; i < 32; i += 8)
        Wt[(size_t)(n0 + i) * KTOT + k0 + tx] = (bf16_t)tile[tx][i];
}

// ---------------------------------------------------------------------------
// X -> packed uint32 per element: low16 = bf16(hi), high16 = bf16(residual).
__global__ void xconv_kernel(const float4* __restrict__ X,
                             uint4* __restrict__ Xpk) {
    int i = blockIdx.x * blockDim.x + threadIdx.x;
    float4 v = X[i];
    float arr[4] = {v.x, v.y, v.z, v.w};
    unsigned pk[4];
#pragma unroll
    for (int j = 0; j < 4; ++j) {
        bf16_t h = (bf16_t)arr[j];
        bf16_t l = (bf16_t)(arr[j] - (float)h);
        pk[j] = (unsigned)__builtin_bit_cast(unsigned short, h) |
                ((unsigned)__builtin_bit_cast(unsigned short, l) << 16);
    }
    Xpk[i] = make_uint4(pk[0], pk[1], pk[2], pk[3]);
}

// ---------------------------------------------------------------------------
__device__ __forceinline__ void unpack16(const unsigned short* s,
                                         bf16x8* hi, bf16x8* lo) {
#pragma unroll
    for (int j = 0; j < 8; ++j) {
        (*hi)[j] = __builtin_bit_cast(bf16_t, s[2 * j]);
        (*lo)[j] = __builtin_bit_cast(bf16_t, s[2 * j + 1]);
    }
}

__device__ __forceinline__ void unpack_u4pair(u32x4 q0, u32x4 q1,
                                              bf16x8* hi, bf16x8* lo) {
    union { u32x4 q[2]; unsigned short s[16]; } v;
    v.q[0] = q0;
    v.q[1] = q1;
    unpack16(v.s, hi, lo);
}

// x fragment: normal cacheable 2x dwordx4.
__device__ __forceinline__ void load_x_frag(const unsigned* p,
                                            bf16x8* hi, bf16x8* lo) {
    union { uint4 q[2]; unsigned short s[16]; } v;
    v.q[0] = *(const uint4*)p;
    v.q[1] = *(const uint4*)(p + 4);
    unpack16(v.s, hi, lo);
}

// ---------------------------------------------------------------------------
// Block b owns h-cols [16b,16b+16). Wave w = K-slice [192w,192w+192), all 4
// gates. hpk ping-pong, frag-major layout:
//   uint idx = (k>>5)*1024 + (b>>4)*512 + (((k>>3)&3)*16 + (b&15))*8 + (k&7)
__global__ __launch_bounds__(512, 2) void lstm_kernel(
    const bf16_t* __restrict__ Wt,
    const unsigned* __restrict__ Xpk,
    unsigned* __restrict__ hpk,
    const float* __restrict__ bias,
    const int* __restrict__ seqlen,
    float* __restrict__ out,
    unsigned* __restrict__ flags) {
    __shared__ float zpart[8][4][32][16];  // 64 KB; tail reused as h-stage

    const int tid  = threadIdx.x;
    const int w    = tid >> 6;
    const int lane = tid & 63;
    const int quad = lane >> 4;
    const int lcol = lane & 15;
    const int hc0  = blockIdx.x * 16;
    const int HW_  = 32768;                // uints per h buffer (B_*H_)
    const int kbBase = w * 6;

    // SRDs for the two h ping-pong buffers (bounds disabled, raw dword).
    const i32x4 srd0 = make_srd(hpk);
    const i32x4 srd1 = make_srd(hpk + HW_);

    // Weight fragments: 4 gates x 6 k-iters, once.
    bf16x8 wreg[24];
#pragma unroll
    for (int g = 0; g < 4; ++g)
#pragma unroll
        for (int it = 0; it < 6; ++it)
            wreg[g * 6 + it] = *(const bf16x8*)(
                Wt + (size_t)(g * H_ + hc0 + lcol) * KTOT + w * 192 + it * 32 +
                quad * 8);

    // Epilogue mapping: 512 threads = one (batch,col) element each.
    const int eb = tid >> 4, ec = tid & 15;
    const int col = hc0 + ec;
    float creg = 0.f;
    const float b0 = bias[col];
    const float b1 = bias[H_ + col];
    const float b2 = bias[2 * H_ + col];
    const float b3 = bias[3 * H_ + col];
    const int slm1 = seqlen[eb] - 1;
    // LDS stage index (destination-ordered within this block's h region).
    const int stageIdx = (eb >> 4) * 256 + ((ec >> 3) * 16 + (eb & 15)) * 8 +
                         (ec & 7);
    // Store-phase constants (R4-verified).
    const int kbB  = (hc0 >> 5) * 1024;    // k-block base (uints)
    const int qlo  = (hc0 >> 4) & 1;       // which quad-pair within k-block
    const int dst0 = kbB + (tid >> 7) * 512 + qlo * 256 + (tid & 127) * 2;

#pragma unroll 1
    for (int t = 0; t < T_; ++t) {
        const i32x4 srdR = (t & 1) ? srd1 : srd0;            // read h(t)
        unsigned*   hw   = hpk + (size_t)((t + 1) & 1) * HW_;  // write h(t+1)

        f32x4 acc[8];
#pragma unroll
        for (int i = 0; i < 8; ++i) acc[i] = (f32x4){0.f, 0.f, 0.f, 0.f};

        // -------- phase 1: x-part (kb >= 32) — independent of h(t) --------
#pragma unroll
        for (int it = 0; it < 6; ++it) {
            int kb = kbBase + it;
            if (kb >= 32) {
                int kx = kb * 32 - H_ + quad * 8;
                bf16x8 a0h, a0l, a1h, a1l;
                load_x_frag(Xpk + ((size_t)lcol * T_ + t) * D_ + kx, &a0h, &a0l);
                load_x_frag(Xpk + ((size_t)(lcol + 16) * T_ + t) * D_ + kx,
                            &a1h, &a1l);
#pragma unroll
                for (int g = 0; g < 4; ++g) {
                    bf16x8 wv = wreg[g * 6 + it];
                    acc[g * 2] = __builtin_amdgcn_mfma_f32_16x16x32_bf16(
                        a0h, wv, acc[g * 2], 0, 0, 0);
                    acc[g * 2] = __builtin_amdgcn_mfma_f32_16x16x32_bf16(
                        a0l, wv, acc[g * 2], 0, 0, 0);
                    acc[g * 2 + 1] = __builtin_amdgcn_mfma_f32_16x16x32_bf16(
                        a1h, wv, acc[g * 2 + 1], 0, 0, 0);
                    acc[g * 2 + 1] = __builtin_amdgcn_mfma_f32_16x16x32_bf16(
                        a1l, wv, acc[g * 2 + 1], 0, 0, 0);
                }
            }
        }

        // ---- barrier poll: packed flags (4 lines), wave 0, sleep backoff ----
        if (tid < 64) {
            for (;;) {
                unsigned v = __hip_atomic_load(flags + tid, __ATOMIC_RELAXED,
                                               __HIP_MEMORY_SCOPE_AGENT);
                if (__all((int)(v >= (unsigned)t))) break;
                __builtin_amdgcn_s_sleep(2);
            }
        }
        __syncthreads();  // S1: h(t) visible to all waves

        // -------- phase 2: h-part (kb < 32), 16B sc0|sc1 buffer loads ----
        // Per lane/iter: bytes at voff, voff+16 (tile0), +2048, +2064 (tile1).
        u32x4 hA0[6], hA1[6], hB0[6], hB1[6];
#pragma unroll
        for (int it = 0; it < 6; ++it) {
            int kb = kbBase + it;
            if (kb < 32) {
                int voff = kb * 4096 + lane * 32;
                hA0[it] = llvm_amdgcn_raw_buffer_load_u32x4(srdR, voff, 0, 17);
                hA1[it] = llvm_amdgcn_raw_buffer_load_u32x4(srdR, voff + 16, 0, 17);
                hB0[it] = llvm_amdgcn_raw_buffer_load_u32x4(srdR, voff + 2048, 0, 17);
                hB1[it] = llvm_amdgcn_raw_buffer_load_u32x4(srdR, voff + 2064, 0, 17);
            }
        }
#pragma unroll
        for (int it = 0; it < 6; ++it) {
            int kb = kbBase + it;
            if (kb < 32) {
                bf16x8 a0h, a0l, a1h, a1l;
                unpack_u4pair(hA0[it], hA1[it], &a0h, &a0l);
                unpack_u4pair(hB0[it], hB1[it], &a1h, &a1l);
#pragma unroll
                for (int g = 0; g < 4; ++g) {
                    bf16x8 wv = wreg[g * 6 + it];
                    acc[g * 2] = __builtin_amdgcn_mfma_f32_16x16x32_bf16(
                        a0h, wv, acc[g * 2], 0, 0, 0);
                    acc[g * 2] = __builtin_amdgcn_mfma_f32_16x16x32_bf16(
                        a0l, wv, acc[g * 2], 0, 0, 0);
                    acc[g * 2 + 1] = __builtin_amdgcn_mfma_f32_16x16x32_bf16(
                        a1h, wv, acc[g * 2 + 1], 0, 0, 0);
                    acc[g * 2 + 1] = __builtin_amdgcn_mfma_f32_16x16x32_bf16(
                        a1l, wv, acc[g * 2 + 1], 0, 0, 0);
                }
            }
        }

#pragma unroll
        for (int g = 0; g < 4; ++g)
#pragma unroll
            for (int r = 0; r < 4; ++r) {
                zpart[w][g][quad * 4 + r][lcol]      = acc[g * 2][r];
                zpart[w][g][16 + quad * 4 + r][lcol] = acc[g * 2 + 1][r];
            }
        __syncthreads();  // S2: zpart complete

        // -------- epilogue: all 512 threads, one (batch,col) each --------
        float zi = b0, zf = b1, zg = b2, zo = b3;
#pragma unroll
        for (int ss = 0; ss < 8; ++ss) {
            zi += zpart[ss][0][eb][ec];
            zf += zpart[ss][1][eb][ec];
            zg += zpart[ss][2][eb][ec];
            zo += zpart[ss][3][eb][ec];
        }
        float ig = 1.f / (1.f + __expf(-zi));
        float fg = 1.f / (1.f + __expf(-zf));
        float og = 1.f / (1.f + __expf(-zo));
        float gg = 1.f - 2.f / (__expf(2.f * zg) + 1.f);
        creg = fg * creg + ig * gg;
        float hn = og * (1.f - 2.f / (__expf(2.f * creg) + 1.f));
        bf16_t hh = (bf16_t)hn;
        bf16_t hl = (bf16_t)(hn - (float)hh);
        unsigned pk = (unsigned)__builtin_bit_cast(unsigned short, hh) |
                      ((unsigned)__builtin_bit_cast(unsigned short, hl) << 16);
        if (slm1 == t) out[eb * H_ + col] = hn;

        __syncthreads();  // S3: everyone done reading zpart -> reuse as stage
        unsigned* stage = (unsigned*)&zpart[0][0][0][0];
        stage[stageIdx] = pk;
        __syncthreads();  // S4: stage complete

        if (tid < 256) {
            unsigned long long val = ((const unsigned long long*)stage)[tid];
            __hip_atomic_store((unsigned long long*)(hw + dst0), val,
                               __ATOMIC_RELAXED, __HIP_MEMORY_SCOPE_AGENT);
        }

        // Drain h stores block-wide, then signal arrival.
        asm volatile("s_waitcnt vmcnt(0)" ::: "memory");
        __syncthreads();  // S5: all waves' h stores at coherence point
        if (tid == 0)
            __hip_atomic_store(flags + blockIdx.x, (unsigned)(t + 1),
                               __ATOMIC_RELAXED, __HIP_MEMORY_SCOPE_AGENT);
    }
}

// ---------------------------------------------------------------------------
extern "C" void kernel_launch(void* const* d_in, const int* in_sizes, int n_in,
                              void* d_out, int out_size, void* d_ws, size_t ws_size,
                              hipStream_t stream) {
    const float* inputs = (const float*)d_in[0];
    const int*   seqlen = (const int*)d_in[1];
    const float* Wx     = (const float*)d_in[2];
    const float* Wh     = (const float*)d_in[3];
    const float* bias   = (const float*)d_in[4];
    float* out = (float*)d_out;

    char* ws = (char*)d_ws;
    size_t o = 0;
    bf16_t*   Wt  = (bf16_t*)(ws + o);   o += (size_t)N4H * KTOT * 2;   // 12.6MB
    unsigned* Xpk = (unsigned*)(ws + o); o += (size_t)B_ * T_ * D_ * 4; // 33.6MB
    unsigned* hpk = (unsigned*)(ws + o); o += (size_t)2 * B_ * H_ * 4;  // 256KB
    unsigned* flg = (unsigned*)(ws + o); o += 256;                      // 64 uints

    wconv_kernel<<<dim3(48, 128), dim3(32, 8), 0, stream>>>(Wx, Wh, Wt);
    xconv_kernel<<<(B_ * T_ * D_ / 4) / 256, 256, 0, stream>>>(
        (const float4*)inputs, (uint4*)Xpk);
    (void)hipMemsetAsync(hpk, 0, (size_t)B_ * H_ * 4, stream);  // ping p=0
    (void)hipMemsetAsync(flg, 0, 256, stream);                  // flags = 0

    lstm_kernel<<<NBLK, 512, 0, stream>>>(Wt, Xpk, hpk, bias, seqlen, out, flg);
}